// Round 13
// baseline (511.669 us; speedup 1.0000x reference)
//
#include <hip/hip_runtime.h>
#include <hip/hip_bf16.h>

// GraphConv: out = relu( scatter_add_{edges}( edge_val * (feat @ W)[edge_col] -> edge_row ) )
// Dtypes: feat/W/edge_val = float32, edge_row/col = int32, OUTPUT = float32.
//
// R12 post-mortem: counts WRITE invariant under copy layout => global atomic RMW costs ~32B
// HBM write-through each (205M atomics=6.55GB in R3; 1.6M=51MB in hist). Only fix: fewer
// global atomics.
// R13: ZERO-global-atomic CSR build = two-level LDS-staged counting sort:
//   A1 per-block LDS hist over 782 coarse buckets -> scanA (1 block) -> A2 LDS-cursor
//   scatter into bucket order -> B per-bucket exact 128-row LDS sort IN PLACE + offsets.

#define N_NODES 100000
#define N_EDGES 1600000
#define D 128
#define GEMM_BLOCKS ((N_NODES + 63) / 64)           // 1563
#define CHUNK_A 8192
#define NBLK_A ((N_EDGES + CHUNK_A - 1) / CHUNK_A)  // 196
#define BUCKETS ((N_NODES + 127) / 128)             // 782 (bucket = row>>7)
#define SCANA_T 1024
#define SCANA_PER ((BUCKETS * NBLK_A + SCANA_T - 1) / SCANA_T)   // 150
#define BCAP 4608                                    // ~57 sigma above mean bucket size 2048

typedef __attribute__((ext_vector_type(8))) short short8;
typedef __attribute__((ext_vector_type(4))) float floatx4;
typedef int  iv2 __attribute__((ext_vector_type(2)));
typedef int  iv4 __attribute__((ext_vector_type(4)));
typedef float fv4 __attribute__((ext_vector_type(4)));

union U16B { uint4 u4; short8 s8; uint u[4]; ushort us[8]; };

__device__ __forceinline__ ushort f32_to_bf16(float f) {
    uint b = __float_as_uint(f);
    return (ushort)((b + 0x7FFFu + ((b >> 16) & 1u)) >> 16);   // RNE; inputs finite
}
__device__ __forceinline__ float bf16_to_f32(ushort u) {
    return __uint_as_float((uint)u << 16);
}

// ---------------- GEMM body: support = bf16( fp32 feat @ fp32 W ), 16KB LDS ----------------
__device__ __forceinline__ void gemm_body(const float* __restrict__ feat,
                                          const float* __restrict__ W,
                                          ushort* __restrict__ support,
                                          ushort* __restrict__ Bp /*64*D*/, int bid) {
    const int tid = threadIdx.x;
    const int wave = tid >> 6, lane = tid & 63;
    const int row0 = bid * 64 + wave * 16;
    const bool active = (row0 < N_NODES);     // wave-uniform
    const int m = lane & 15, g = lane >> 4;

    floatx4 acc[8];
    const floatx4 z = {0.f, 0.f, 0.f, 0.f};
    #pragma unroll
    for (int t = 0; t < 8; t++) acc[t] = z;

    const float* arow = feat + (size_t)(row0 + m) * D;
    #pragma unroll
    for (int h = 0; h < 2; h++) {             // two k-halves of 64
        if (h) __syncthreads();
        for (int e = tid; e < 64 * D; e += 256) {
            int kk = e >> 7, n = e & 127;
            Bp[(((kk >> 3) * D + n) << 3) | (kk & 7)] = f32_to_bf16(W[(h * 64 + kk) * D + n]);
        }
        __syncthreads();
        if (active) {
            #pragma unroll
            for (int ss = 0; ss < 2; ss++) {
                const int s = h * 2 + ss;
                float4 a0 = *(const float4*)(arow + s * 32 + g * 8);
                float4 a1 = *(const float4*)(arow + s * 32 + g * 8 + 4);
                U16B a;
                a.us[0] = f32_to_bf16(a0.x); a.us[1] = f32_to_bf16(a0.y);
                a.us[2] = f32_to_bf16(a0.z); a.us[3] = f32_to_bf16(a0.w);
                a.us[4] = f32_to_bf16(a1.x); a.us[5] = f32_to_bf16(a1.y);
                a.us[6] = f32_to_bf16(a1.z); a.us[7] = f32_to_bf16(a1.w);
                #pragma unroll
                for (int t = 0; t < 8; t++) {
                    const int chunk = (ss * 4 + g) * D + t * 16 + m;
                    U16B b; b.u4 = *(const uint4*)(Bp + chunk * 8);
                    acc[t] = __builtin_amdgcn_mfma_f32_16x16x32_bf16(a.s8, b.s8, acc[t], 0, 0, 0);
                }
            }
        }
    }
    if (active) {
        // C/D: col = lane&15, row = (lane>>4)*4 + reg  (m89-verified)
        #pragma unroll
        for (int t = 0; t < 8; t++) {
            #pragma unroll
            for (int r = 0; r < 4; r++) {
                const int row = row0 + g * 4 + r;
                const int col = t * 16 + m;
                support[(size_t)row * D + col] = f32_to_bf16(acc[t][r]);
            }
        }
    }
}

__global__ __launch_bounds__(256) void gemm_kernel(const float* __restrict__ feat,
                                                   const float* __restrict__ W,
                                                   ushort* __restrict__ support) {
    __shared__ ushort Bp[64 * D];
    gemm_body(feat, W, support, Bp, blockIdx.x);
}

// ---------------- A1: per-block LDS histogram over coarse buckets (NO global atomics) -------
__global__ __launch_bounds__(256) void binhist_kernel(const int* __restrict__ edge_row,
                                                      int* __restrict__ histA) { // [blk][BUCKETS]
    __shared__ int hist[BUCKETS];
    const int tid = threadIdx.x, blk = blockIdx.x;
    for (int i = tid; i < BUCKETS; i += 256) hist[i] = 0;
    __syncthreads();
    const int base = blk * CHUNK_A;
    #pragma unroll
    for (int k = 0; k < CHUNK_A / 256; k++) {
        const int e = base + k * 256 + tid;
        if (e < N_EDGES) atomicAdd(&hist[edge_row[e] >> 7], 1);   // LDS atomic
    }
    __syncthreads();
    for (int i = tid; i < BUCKETS; i += 256) histA[blk * BUCKETS + i] = hist[i];
}

// ---------------- scanA: bucket-major exclusive scan of [BUCKETS][NBLK_A], one block --------
__global__ __launch_bounds__(SCANA_T) void scanA_kernel(const int* __restrict__ histA,
                                                        int* __restrict__ baseT,     // [blk][BUCKETS]
                                                        int* __restrict__ bucketOff) {// [BUCKETS+1]
    __shared__ int wsum[SCANA_T / 64];
    const int tid = threadIdx.x, lane = tid & 63, wave = tid >> 6;
    const int f0 = tid * SCANA_PER;
    const int TOTALF = BUCKETS * NBLK_A;

    int sum = 0;
    for (int k = 0; k < SCANA_PER; k++) {
        const int f = f0 + k;
        if (f < TOTALF) {
            const int bucket = f / NBLK_A, blk = f - bucket * NBLK_A;
            sum += histA[blk * BUCKETS + bucket];
        }
    }
    int x = sum;                               // inclusive wave scan
    #pragma unroll
    for (int d = 1; d < 64; d <<= 1) {
        int y = __shfl_up(x, d, 64);
        if (lane >= d) x += y;
    }
    if (lane == 63) wsum[wave] = x;
    __syncthreads();
    if (tid == 0) {
        int run = 0;
        #pragma unroll
        for (int w = 0; w < SCANA_T / 64; w++) { int t = wsum[w]; wsum[w] = run; run += t; }
    }
    __syncthreads();
    int run = wsum[wave] + (x - sum);          // exclusive prefix for this thread's range
    for (int k = 0; k < SCANA_PER; k++) {
        const int f = f0 + k;
        if (f < TOTALF) {
            const int bucket = f / NBLK_A, blk = f - bucket * NBLK_A;
            if (blk == 0) bucketOff[bucket] = run;
            baseT[blk * BUCKETS + bucket] = run;
            run += histA[blk * BUCKETS + bucket];
        }
    }
    if (tid == 0) bucketOff[BUCKETS] = N_EDGES;
}

// ---------------- A2: LDS-cursor scatter into bucket-sorted order (NO global atomics) -------
// pack = (rowLocal<<17) | col  (rowLocal<128, col<131072)
__global__ __launch_bounds__(256) void binscatter_kernel(const int* __restrict__ edge_row,
                                                         const int* __restrict__ edge_col,
                                                         const float* __restrict__ edge_val,
                                                         const int* __restrict__ baseT,
                                                         iv2* __restrict__ sorted) {
    __shared__ int cur[BUCKETS];
    const int tid = threadIdx.x, blk = blockIdx.x;
    for (int i = tid; i < BUCKETS; i += 256) cur[i] = baseT[blk * BUCKETS + i];
    __syncthreads();
    const int base = blk * CHUNK_A;
    #pragma unroll
    for (int k = 0; k < CHUNK_A / 256; k++) {
        const int e = base + k * 256 + tid;
        if (e < N_EDGES) {
            const int r = edge_row[e];
            const int p = atomicAdd(&cur[r >> 7], 1);   // LDS atomic; block-private region
            iv2 pk;
            pk.x = ((r & 127) << 17) | edge_col[e];
            pk.y = __float_as_int(edge_val[e]);
            sorted[p] = pk;      // normal store: same-XCD L2 write-combining
        }
    }
}

// ---------------- B: per-bucket exact 128-row sort IN PLACE + offsets (LDS only) ------------
__global__ __launch_bounds__(256) void bucket_sort_kernel(const int* __restrict__ bucketOff,
                                                          iv2* __restrict__ sorted,
                                                          int* __restrict__ offsets) {
    __shared__ iv2 ebuf[BCAP];
    __shared__ int cnt[128], cur[128];
    __shared__ int wtot;
    const int tid = threadIdx.x, b = blockIdx.x;
    const int s = bucketOff[b], eEnd = bucketOff[b + 1];
    const int nE = eEnd - s;
    if (tid < 128) cnt[tid] = 0;
    __syncthreads();
    for (int i = tid; i < nE; i += 256) {      // stage fully BEFORE any overwrite
        iv2 e = sorted[s + i];
        ebuf[i] = e;
        atomicAdd(&cnt[e.x >> 17], 1);
    }
    __syncthreads();
    // exclusive scan of cnt[128] via waves 0-1
    const int lane = tid & 63;
    const int myc = (tid < 128) ? cnt[tid] : 0;
    int x = myc;
    #pragma unroll
    for (int d = 1; d < 64; d <<= 1) {
        int y = __shfl_up(x, d, 64);
        if (lane >= d) x += y;
    }
    if (tid == 63) wtot = x;
    __syncthreads();
    const int excl = x + ((tid >= 64 && tid < 128) ? wtot : 0) - myc;
    if (tid < 128) cur[tid] = excl;
    const int row = (b << 7) + tid;
    if (tid < 128 && row < N_NODES) offsets[row] = s + excl;
    if (b == BUCKETS - 1 && tid == 0) offsets[N_NODES] = N_EDGES;
    __syncthreads();
    for (int i = tid; i < nE; i += 256) {
        iv2 e = ebuf[i];
        const int rl = e.x >> 17;
        const int p = atomicAdd(&cur[rl], 1);  // LDS atomic
        iv2 o; o.x = e.x & 0x1FFFF; o.y = e.y; // (col, val) for accum
        sorted[s + p] = o;
    }
}

// ---------------- Accumulate: 16 lanes/row, 4-wide unroll, fused ReLU -----------------------
__global__ __launch_bounds__(256) void accum_kernel(const ushort* __restrict__ support,
                                                    const int* __restrict__ offsets,
                                                    const iv2* __restrict__ epack,
                                                    float* __restrict__ out) {
    const int tid = threadIdx.x;
    const int row  = (blockIdx.x * 256 + tid) >> 4;       // one 16-lane group per row
    const int part = tid & 15;
    if (row >= N_NODES) return;

    const int start = offsets[row], end = offsets[row + 1];
    float acc0[8], acc1[8];
    #pragma unroll
    for (int i = 0; i < 8; i++) { acc0[i] = 0.f; acc1[i] = 0.f; }

    int e = start;
    if ((e & 1) && e < end) {                 // align to 16B for iv4 loads
        const iv2 pa = epack[e];
        U16B sa; sa.u4 = *(const uint4*)(support + (size_t)pa.x * D + part * 8);
        const float va = __int_as_float(pa.y);
        #pragma unroll
        for (int i = 0; i < 8; i++) acc0[i] += bf16_to_f32(sa.us[i]) * va;
        ++e;
    }
    for (; e + 3 < end; e += 4) {             // 4 gathers in flight
        const iv4 qa = ((const iv4*)(epack + e))[0];
        const iv4 qb = ((const iv4*)(epack + e))[1];
        U16B s0; s0.u4 = *(const uint4*)(support + (size_t)qa.x * D + part * 8);
        U16B s1; s1.u4 = *(const uint4*)(support + (size_t)qa.z * D + part * 8);
        U16B s2; s2.u4 = *(const uint4*)(support + (size_t)qb.x * D + part * 8);
        U16B s3; s3.u4 = *(const uint4*)(support + (size_t)qb.z * D + part * 8);
        const float v0 = __int_as_float(qa.y);
        const float v1 = __int_as_float(qa.w);
        const float v2 = __int_as_float(qb.y);
        const float v3 = __int_as_float(qb.w);
        #pragma unroll
        for (int i = 0; i < 8; i++) {
            acc0[i] += bf16_to_f32(s0.us[i]) * v0;
            acc1[i] += bf16_to_f32(s1.us[i]) * v1;
            acc0[i] += bf16_to_f32(s2.us[i]) * v2;
            acc1[i] += bf16_to_f32(s3.us[i]) * v3;
        }
    }
    for (; e < end; ++e) {
        const iv2 pa = epack[e];
        U16B sa; sa.u4 = *(const uint4*)(support + (size_t)pa.x * D + part * 8);
        const float va = __int_as_float(pa.y);
        #pragma unroll
        for (int i = 0; i < 8; i++) acc0[i] += bf16_to_f32(sa.us[i]) * va;
    }

    fv4 lo, hi;
    lo.x = fmaxf(acc0[0] + acc1[0], 0.f); lo.y = fmaxf(acc0[1] + acc1[1], 0.f);
    lo.z = fmaxf(acc0[2] + acc1[2], 0.f); lo.w = fmaxf(acc0[3] + acc1[3], 0.f);
    hi.x = fmaxf(acc0[4] + acc1[4], 0.f); hi.y = fmaxf(acc0[5] + acc1[5], 0.f);
    hi.z = fmaxf(acc0[6] + acc1[6], 0.f); hi.w = fmaxf(acc0[7] + acc1[7], 0.f);
    float* dst = out + (size_t)row * D + part * 8;
    __builtin_nontemporal_store(lo, (fv4*)dst);
    __builtin_nontemporal_store(hi, (fv4*)(dst + 4));
}

// ================= Fallback path (R3 atomic spmm) if ws too small ===========================
__global__ __launch_bounds__(256) void zero_f4_kernel(float4* __restrict__ acc, int n4) {
    int i = blockIdx.x * 256 + threadIdx.x;
    if (i < n4) acc[i] = make_float4(0.f, 0.f, 0.f, 0.f);
}
__global__ __launch_bounds__(256) void spmm_kernel(const ushort* __restrict__ support,
                                                   const float* __restrict__ edge_val,
                                                   const int* __restrict__ edge_row,
                                                   const int* __restrict__ edge_col,
                                                   float* __restrict__ out) {
    const long gtid = (long)blockIdx.x * 256 + threadIdx.x;
    const int edge = (int)(gtid >> 4);
    const int part = (int)(gtid & 15);
    if (edge >= N_EDGES) return;
    const int col = edge_col[edge];
    const int row = edge_row[edge];
    const float v = edge_val[edge];
    U16B s; s.u4 = *(const uint4*)(support + (size_t)col * D + part * 8);
    float* dst = out + (size_t)row * D + part * 8;
    #pragma unroll
    for (int i = 0; i < 8; i++) unsafeAtomicAdd(dst + i, bf16_to_f32(s.us[i]) * v);
}
__global__ __launch_bounds__(256) void relu_kernel(float4* __restrict__ out, int n4) {
    int i = blockIdx.x * 256 + threadIdx.x;
    if (i >= n4) return;
    float4 a = out[i];
    a.x = fmaxf(a.x, 0.f); a.y = fmaxf(a.y, 0.f);
    a.z = fmaxf(a.z, 0.f); a.w = fmaxf(a.w, 0.f);
    out[i] = a;
}

extern "C" void kernel_launch(void* const* d_in, const int* in_sizes, int n_in,
                              void* d_out, int out_size, void* d_ws, size_t ws_size,
                              hipStream_t stream) {
    (void)in_sizes; (void)n_in; (void)out_size;
    const float* feat     = (const float*)d_in[0];
    const float* W        = (const float*)d_in[1];
    const float* edge_val = (const float*)d_in[2];
    const int*   edge_row = (const int*)d_in[3];
    const int*   edge_col = (const int*)d_in[4];
    float* out = (float*)d_out;

    // ws layout (~40.1 MB, all 16B-aligned slots)
    char* ws = (char*)d_ws;
    size_t o = 0;
    ushort* support  = (ushort*)(ws + o); o += (size_t)N_NODES * D * sizeof(ushort);       // 25.6 MB
    int*    offsets  = (int*)(ws + o);    o += ((size_t)(N_NODES + 1) * 4 + 15) & ~15ull;  // 0.4 MB
    int*    histA    = (int*)(ws + o);    o += ((size_t)NBLK_A * BUCKETS * 4 + 15) & ~15ull; // 613 KB
    int*    baseT    = (int*)(ws + o);    o += ((size_t)NBLK_A * BUCKETS * 4 + 15) & ~15ull; // 613 KB
    int*    bucketOff= (int*)(ws + o);    o += ((size_t)(BUCKETS + 1) * 4 + 15) & ~15ull;
    iv2*    sorted   = (iv2*)(ws + o);    o += (size_t)N_EDGES * 8;                        // 12.8 MB
    const size_t needed = o;

    if (ws_size >= needed) {
        // Zero-global-atomic CSR build + gemm + accum
        gemm_kernel<<<GEMM_BLOCKS, 256, 0, stream>>>(feat, W, support);
        binhist_kernel<<<NBLK_A, 256, 0, stream>>>(edge_row, histA);
        scanA_kernel<<<1, SCANA_T, 0, stream>>>(histA, baseT, bucketOff);
        binscatter_kernel<<<NBLK_A, 256, 0, stream>>>(edge_row, edge_col, edge_val,
                                                      baseT, sorted);
        bucket_sort_kernel<<<BUCKETS, 256, 0, stream>>>(bucketOff, sorted, offsets);
        accum_kernel<<<(N_NODES * 16 + 255) / 256, 256, 0, stream>>>(support, offsets,
                                                                     sorted, out);
    } else {
        // R3 fallback: atomic spmm into d_out
        const int n4 = N_NODES * D / 4;
        zero_f4_kernel<<<(n4 + 255) / 256, 256, 0, stream>>>((float4*)out, n4);
        gemm_kernel<<<GEMM_BLOCKS, 256, 0, stream>>>(feat, W, support);
        spmm_kernel<<<(int)(((long)N_EDGES * 16 + 255) / 256), 256, 0, stream>>>(
            support, edge_val, edge_row, edge_col, out);
        relu_kernel<<<(n4 + 255) / 256, 256, 0, stream>>>((float4*)out, n4);
    }
}

// Round 14
// 273.933 us; speedup vs baseline: 1.8679x; 1.8679x over previous
//
#include <hip/hip_runtime.h>
#include <hip/hip_bf16.h>

// GraphConv: out = relu( scatter_add_{edges}( edge_val * (feat @ W)[edge_col] -> edge_row ) )
// Dtypes: feat/W/edge_val = float32, edge_row/col = int32, OUTPUT = float32.
//
// R13 post-mortem: zero-atomic sort validated, but scanA (single-block, transposed strided
// reads, int div) = 258us @ 0.16% occupancy.
// R14: A1 writes histogram TRANSPOSED (histT[bucket*NBLK_A+blk]) so the scan order is a
// contiguous 153,272-int array; 150-block decoupled-lookback scan (R11-proven); A2 reads
// its cursors from the transposed bases. Everything else identical to R13.

#define N_NODES 100000
#define N_EDGES 1600000
#define D 128
#define GEMM_BLOCKS ((N_NODES + 63) / 64)           // 1563
#define CHUNK_A 8192
#define NBLK_A ((N_EDGES + CHUNK_A - 1) / CHUNK_A)  // 196
#define BUCKETS ((N_NODES + 127) / 128)             // 782 (bucket = row>>7)
#define N_SCAN (BUCKETS * NBLK_A)                   // 153,272
#define SCAN_BLK ((N_SCAN + 1023) / 1024)           // 150
#define BCAP 4608                                    // max bucket size (mean 2048)

typedef __attribute__((ext_vector_type(8))) short short8;
typedef __attribute__((ext_vector_type(4))) float floatx4;
typedef int  iv2 __attribute__((ext_vector_type(2)));
typedef int  iv4 __attribute__((ext_vector_type(4)));
typedef float fv4 __attribute__((ext_vector_type(4)));

union U16B { uint4 u4; short8 s8; uint u[4]; ushort us[8]; };

__device__ __forceinline__ ushort f32_to_bf16(float f) {
    uint b = __float_as_uint(f);
    return (ushort)((b + 0x7FFFu + ((b >> 16) & 1u)) >> 16);   // RNE; inputs finite
}
__device__ __forceinline__ float bf16_to_f32(ushort u) {
    return __uint_as_float((uint)u << 16);
}

// ---------------- GEMM body: support = bf16( fp32 feat @ fp32 W ), 16KB LDS ----------------
__device__ __forceinline__ void gemm_body(const float* __restrict__ feat,
                                          const float* __restrict__ W,
                                          ushort* __restrict__ support,
                                          ushort* __restrict__ Bp /*64*D*/, int bid) {
    const int tid = threadIdx.x;
    const int wave = tid >> 6, lane = tid & 63;
    const int row0 = bid * 64 + wave * 16;
    const bool active = (row0 < N_NODES);     // wave-uniform
    const int m = lane & 15, g = lane >> 4;

    floatx4 acc[8];
    const floatx4 z = {0.f, 0.f, 0.f, 0.f};
    #pragma unroll
    for (int t = 0; t < 8; t++) acc[t] = z;

    const float* arow = feat + (size_t)(row0 + m) * D;
    #pragma unroll
    for (int h = 0; h < 2; h++) {             // two k-halves of 64
        if (h) __syncthreads();
        for (int e = tid; e < 64 * D; e += 256) {
            int kk = e >> 7, n = e & 127;
            Bp[(((kk >> 3) * D + n) << 3) | (kk & 7)] = f32_to_bf16(W[(h * 64 + kk) * D + n]);
        }
        __syncthreads();
        if (active) {
            #pragma unroll
            for (int ss = 0; ss < 2; ss++) {
                const int s = h * 2 + ss;
                float4 a0 = *(const float4*)(arow + s * 32 + g * 8);
                float4 a1 = *(const float4*)(arow + s * 32 + g * 8 + 4);
                U16B a;
                a.us[0] = f32_to_bf16(a0.x); a.us[1] = f32_to_bf16(a0.y);
                a.us[2] = f32_to_bf16(a0.z); a.us[3] = f32_to_bf16(a0.w);
                a.us[4] = f32_to_bf16(a1.x); a.us[5] = f32_to_bf16(a1.y);
                a.us[6] = f32_to_bf16(a1.z); a.us[7] = f32_to_bf16(a1.w);
                #pragma unroll
                for (int t = 0; t < 8; t++) {
                    const int chunk = (ss * 4 + g) * D + t * 16 + m;
                    U16B b; b.u4 = *(const uint4*)(Bp + chunk * 8);
                    acc[t] = __builtin_amdgcn_mfma_f32_16x16x32_bf16(a.s8, b.s8, acc[t], 0, 0, 0);
                }
            }
        }
    }
    if (active) {
        // C/D: col = lane&15, row = (lane>>4)*4 + reg  (m89-verified)
        #pragma unroll
        for (int t = 0; t < 8; t++) {
            #pragma unroll
            for (int r = 0; r < 4; r++) {
                const int row = row0 + g * 4 + r;
                const int col = t * 16 + m;
                support[(size_t)row * D + col] = f32_to_bf16(acc[t][r]);
            }
        }
    }
}

__global__ __launch_bounds__(256) void gemm_kernel(const float* __restrict__ feat,
                                                   const float* __restrict__ W,
                                                   ushort* __restrict__ support) {
    __shared__ ushort Bp[64 * D];
    gemm_body(feat, W, support, Bp, blockIdx.x);
}

// ---------------- A1: per-block LDS histogram, TRANSPOSED write; block 0 zeroes st ----------
__global__ __launch_bounds__(256) void binhist_kernel(const int* __restrict__ edge_row,
                                                      int* __restrict__ histT,  // [bucket][blk]
                                                      uint* __restrict__ st) {
    __shared__ int hist[BUCKETS];
    const int tid = threadIdx.x, blk = blockIdx.x;
    if (blk == 0 && tid < 256) st[tid] = 0;          // lookback state for scan (256 >= SCAN_BLK)
    for (int i = tid; i < BUCKETS; i += 256) hist[i] = 0;
    __syncthreads();
    const int base = blk * CHUNK_A;
    #pragma unroll
    for (int k = 0; k < CHUNK_A / 256; k++) {
        const int e = base + k * 256 + tid;
        if (e < N_EDGES) atomicAdd(&hist[edge_row[e] >> 7], 1);   // LDS atomic
    }
    __syncthreads();
    for (int i = tid; i < BUCKETS; i += 256) histT[i * NBLK_A + blk] = hist[i];
}

// ---------------- scan: 150-block decoupled-lookback exclusive scan over histT --------------
// st[b] = (state<<30)|value; 1 = aggregate published, 2 = inclusive prefix published.
__global__ __launch_bounds__(1024) void scan_kernel(const int* __restrict__ histT,
                                                    int* __restrict__ baseS,
                                                    int* __restrict__ bucketOff,
                                                    uint* __restrict__ st) {
    __shared__ int wsum[16];
    __shared__ int s_run, s_base;
    const int tid = threadIdx.x, b = blockIdx.x;
    const int gid = b * 1024 + tid;
    const int lane = tid & 63, wave = tid >> 6;

    const int v = (gid < N_SCAN) ? histT[gid] : 0;
    int x = v;                                 // inclusive wave scan
    #pragma unroll
    for (int d = 1; d < 64; d <<= 1) {
        int y = __shfl_up(x, d, 64);
        if (lane >= d) x += y;
    }
    if (lane == 63) wsum[wave] = x;
    __syncthreads();
    if (tid == 0) {
        int run = 0;
        #pragma unroll
        for (int w = 0; w < 16; w++) { int t = wsum[w]; wsum[w] = run; run += t; }
        s_run = run;
        __hip_atomic_store(&st[b], (1u << 30) | (uint)run,
                           __ATOMIC_RELEASE, __HIP_MEMORY_SCOPE_AGENT);
    }
    __syncthreads();
    if (wave == 0) {                           // 64-wide parallel lookback
        int P = 0;
        int base = b;
        bool done = (b == 0);
        while (!done) {
            const int j = base - 1 - lane;
            uint w;
            if (j >= 0) {
                do {
                    w = __hip_atomic_load(&st[j], __ATOMIC_ACQUIRE, __HIP_MEMORY_SCOPE_AGENT);
                } while ((w >> 30) == 0u);
            } else w = 2u << 30;
            const unsigned long long m2 = __ballot((w >> 30) == 2u);
            int contrib;
            if (m2) {
                const int fl = (int)__ffsll(m2) - 1;
                contrib = (lane <= fl) ? (int)(w & 0x3FFFFFFFu) : 0;
                done = true;
            } else {
                contrib = (int)(w & 0x3FFFFFFFu);
                base -= 64;
            }
            #pragma unroll
            for (int mm = 1; mm < 64; mm <<= 1) contrib += __shfl_xor(contrib, mm, 64);
            P += contrib;
        }
        if (lane == 0) {
            __hip_atomic_store(&st[b], (2u << 30) | (uint)(P + s_run),
                               __ATOMIC_RELEASE, __HIP_MEMORY_SCOPE_AGENT);
            s_base = P;
        }
    }
    __syncthreads();
    if (gid < N_SCAN) {
        const int excl = s_base + wsum[wave] + (x - v);
        baseS[gid] = excl;
        const int bucket = gid / NBLK_A;       // boundary detect (cheap: only for multiples)
        if (gid - bucket * NBLK_A == 0) bucketOff[bucket] = excl;
    }
    if (gid == 0) bucketOff[BUCKETS] = N_EDGES;
}

// ---------------- A2: LDS-cursor scatter into bucket-sorted order (NO global atomics) -------
// pack = (rowLocal<<17) | col  (rowLocal<128, col<131072)
__global__ __launch_bounds__(256) void binscatter_kernel(const int* __restrict__ edge_row,
                                                         const int* __restrict__ edge_col,
                                                         const float* __restrict__ edge_val,
                                                         const int* __restrict__ baseS,
                                                         iv2* __restrict__ sorted) {
    __shared__ int cur[BUCKETS];
    const int tid = threadIdx.x, blk = blockIdx.x;
    for (int i = tid; i < BUCKETS; i += 256) cur[i] = baseS[i * NBLK_A + blk];
    __syncthreads();
    const int base = blk * CHUNK_A;
    #pragma unroll
    for (int k = 0; k < CHUNK_A / 256; k++) {
        const int e = base + k * 256 + tid;
        if (e < N_EDGES) {
            const int r = edge_row[e];
            const int p = atomicAdd(&cur[r >> 7], 1);   // LDS atomic; block-private region
            iv2 pk;
            pk.x = ((r & 127) << 17) | edge_col[e];
            pk.y = __float_as_int(edge_val[e]);
            sorted[p] = pk;
        }
    }
}

// ---------------- B: per-bucket exact 128-row sort IN PLACE + offsets (LDS only) ------------
__global__ __launch_bounds__(256) void bucket_sort_kernel(const int* __restrict__ bucketOff,
                                                          iv2* __restrict__ sorted,
                                                          int* __restrict__ offsets) {
    __shared__ iv2 ebuf[BCAP];
    __shared__ int cnt[128], cur[128];
    __shared__ int wtot;
    const int tid = threadIdx.x, b = blockIdx.x;
    const int s = bucketOff[b], eEnd = bucketOff[b + 1];
    const int nE = eEnd - s;
    if (tid < 128) cnt[tid] = 0;
    __syncthreads();
    for (int i = tid; i < nE; i += 256) {      // stage fully BEFORE any overwrite
        iv2 e = sorted[s + i];
        ebuf[i] = e;
        atomicAdd(&cnt[e.x >> 17], 1);
    }
    __syncthreads();
    const int lane = tid & 63;
    const int myc = (tid < 128) ? cnt[tid] : 0;
    int x = myc;
    #pragma unroll
    for (int d = 1; d < 64; d <<= 1) {
        int y = __shfl_up(x, d, 64);
        if (lane >= d) x += y;
    }
    if (tid == 63) wtot = x;
    __syncthreads();
    const int excl = x + ((tid >= 64 && tid < 128) ? wtot : 0) - myc;
    if (tid < 128) cur[tid] = excl;
    const int row = (b << 7) + tid;
    if (tid < 128 && row < N_NODES) offsets[row] = s + excl;
    if (b == BUCKETS - 1 && tid == 0) offsets[N_NODES] = N_EDGES;
    __syncthreads();
    for (int i = tid; i < nE; i += 256) {
        iv2 e = ebuf[i];
        const int rl = e.x >> 17;
        const int p = atomicAdd(&cur[rl], 1);  // LDS atomic
        iv2 o; o.x = e.x & 0x1FFFF; o.y = e.y; // (col, val) for accum
        sorted[s + p] = o;
    }
}

// ---------------- Accumulate: 16 lanes/row, 4-wide unroll, fused ReLU -----------------------
__global__ __launch_bounds__(256) void accum_kernel(const ushort* __restrict__ support,
                                                    const int* __restrict__ offsets,
                                                    const iv2* __restrict__ epack,
                                                    float* __restrict__ out) {
    const int tid = threadIdx.x;
    const int row  = (blockIdx.x * 256 + tid) >> 4;       // one 16-lane group per row
    const int part = tid & 15;
    if (row >= N_NODES) return;

    const int start = offsets[row], end = offsets[row + 1];
    float acc0[8], acc1[8];
    #pragma unroll
    for (int i = 0; i < 8; i++) { acc0[i] = 0.f; acc1[i] = 0.f; }

    int e = start;
    if ((e & 1) && e < end) {                 // align to 16B for iv4 loads
        const iv2 pa = epack[e];
        U16B sa; sa.u4 = *(const uint4*)(support + (size_t)pa.x * D + part * 8);
        const float va = __int_as_float(pa.y);
        #pragma unroll
        for (int i = 0; i < 8; i++) acc0[i] += bf16_to_f32(sa.us[i]) * va;
        ++e;
    }
    for (; e + 3 < end; e += 4) {             // 4 gathers in flight
        const iv4 qa = ((const iv4*)(epack + e))[0];
        const iv4 qb = ((const iv4*)(epack + e))[1];
        U16B s0; s0.u4 = *(const uint4*)(support + (size_t)qa.x * D + part * 8);
        U16B s1; s1.u4 = *(const uint4*)(support + (size_t)qa.z * D + part * 8);
        U16B s2; s2.u4 = *(const uint4*)(support + (size_t)qb.x * D + part * 8);
        U16B s3; s3.u4 = *(const uint4*)(support + (size_t)qb.z * D + part * 8);
        const float v0 = __int_as_float(qa.y);
        const float v1 = __int_as_float(qa.w);
        const float v2 = __int_as_float(qb.y);
        const float v3 = __int_as_float(qb.w);
        #pragma unroll
        for (int i = 0; i < 8; i++) {
            acc0[i] += bf16_to_f32(s0.us[i]) * v0;
            acc1[i] += bf16_to_f32(s1.us[i]) * v1;
            acc0[i] += bf16_to_f32(s2.us[i]) * v2;
            acc1[i] += bf16_to_f32(s3.us[i]) * v3;
        }
    }
    for (; e < end; ++e) {
        const iv2 pa = epack[e];
        U16B sa; sa.u4 = *(const uint4*)(support + (size_t)pa.x * D + part * 8);
        const float va = __int_as_float(pa.y);
        #pragma unroll
        for (int i = 0; i < 8; i++) acc0[i] += bf16_to_f32(sa.us[i]) * va;
    }

    fv4 lo, hi;
    lo.x = fmaxf(acc0[0] + acc1[0], 0.f); lo.y = fmaxf(acc0[1] + acc1[1], 0.f);
    lo.z = fmaxf(acc0[2] + acc1[2], 0.f); lo.w = fmaxf(acc0[3] + acc1[3], 0.f);
    hi.x = fmaxf(acc0[4] + acc1[4], 0.f); hi.y = fmaxf(acc0[5] + acc1[5], 0.f);
    hi.z = fmaxf(acc0[6] + acc1[6], 0.f); hi.w = fmaxf(acc0[7] + acc1[7], 0.f);
    float* dst = out + (size_t)row * D + part * 8;
    __builtin_nontemporal_store(lo, (fv4*)dst);
    __builtin_nontemporal_store(hi, (fv4*)(dst + 4));
}

// ================= Fallback path (R3 atomic spmm) if ws too small ===========================
__global__ __launch_bounds__(256) void zero_f4_kernel(float4* __restrict__ acc, int n4) {
    int i = blockIdx.x * 256 + threadIdx.x;
    if (i < n4) acc[i] = make_float4(0.f, 0.f, 0.f, 0.f);
}
__global__ __launch_bounds__(256) void spmm_kernel(const ushort* __restrict__ support,
                                                   const float* __restrict__ edge_val,
                                                   const int* __restrict__ edge_row,
                                                   const int* __restrict__ edge_col,
                                                   float* __restrict__ out) {
    const long gtid = (long)blockIdx.x * 256 + threadIdx.x;
    const int edge = (int)(gtid >> 4);
    const int part = (int)(gtid & 15);
    if (edge >= N_EDGES) return;
    const int col = edge_col[edge];
    const int row = edge_row[edge];
    const float v = edge_val[edge];
    U16B s; s.u4 = *(const uint4*)(support + (size_t)col * D + part * 8);
    float* dst = out + (size_t)row * D + part * 8;
    #pragma unroll
    for (int i = 0; i < 8; i++) unsafeAtomicAdd(dst + i, bf16_to_f32(s.us[i]) * v);
}
__global__ __launch_bounds__(256) void relu_kernel(float4* __restrict__ out, int n4) {
    int i = blockIdx.x * 256 + threadIdx.x;
    if (i >= n4) return;
    float4 a = out[i];
    a.x = fmaxf(a.x, 0.f); a.y = fmaxf(a.y, 0.f);
    a.z = fmaxf(a.z, 0.f); a.w = fmaxf(a.w, 0.f);
    out[i] = a;
}

extern "C" void kernel_launch(void* const* d_in, const int* in_sizes, int n_in,
                              void* d_out, int out_size, void* d_ws, size_t ws_size,
                              hipStream_t stream) {
    (void)in_sizes; (void)n_in; (void)out_size;
    const float* feat     = (const float*)d_in[0];
    const float* W        = (const float*)d_in[1];
    const float* edge_val = (const float*)d_in[2];
    const int*   edge_row = (const int*)d_in[3];
    const int*   edge_col = (const int*)d_in[4];
    float* out = (float*)d_out;

    // ws layout (~40.1 MB, all 16B-aligned slots)
    char* ws = (char*)d_ws;
    size_t o = 0;
    ushort* support  = (ushort*)(ws + o); o += (size_t)N_NODES * D * sizeof(ushort);        // 25.6 MB
    int*    offsets  = (int*)(ws + o);    o += ((size_t)(N_NODES + 1) * 4 + 15) & ~15ull;   // 0.4 MB
    int*    histT    = (int*)(ws + o);    o += ((size_t)N_SCAN * 4 + 15) & ~15ull;          // 613 KB
    int*    baseS    = (int*)(ws + o);    o += ((size_t)N_SCAN * 4 + 15) & ~15ull;          // 613 KB
    int*    bucketOff= (int*)(ws + o);    o += ((size_t)(BUCKETS + 1) * 4 + 15) & ~15ull;
    uint*   st       = (uint*)(ws + o);   o += 256 * 4;                                     // lookback
    iv2*    sorted   = (iv2*)(ws + o);    o += (size_t)N_EDGES * 8;                         // 12.8 MB
    const size_t needed = o;

    if (ws_size >= needed) {
        // Zero-global-atomic CSR build + gemm + accum
        gemm_kernel<<<GEMM_BLOCKS, 256, 0, stream>>>(feat, W, support);
        binhist_kernel<<<NBLK_A, 256, 0, stream>>>(edge_row, histT, st);
        scan_kernel<<<SCAN_BLK, 1024, 0, stream>>>(histT, baseS, bucketOff, st);
        binscatter_kernel<<<NBLK_A, 256, 0, stream>>>(edge_row, edge_col, edge_val,
                                                      baseS, sorted);
        bucket_sort_kernel<<<BUCKETS, 256, 0, stream>>>(bucketOff, sorted, offsets);
        accum_kernel<<<(N_NODES * 16 + 255) / 256, 256, 0, stream>>>(support, offsets,
                                                                     sorted, out);
    } else {
        // R3 fallback: atomic spmm into d_out
        const int n4 = N_NODES * D / 4;
        zero_f4_kernel<<<(n4 + 255) / 256, 256, 0, stream>>>((float4*)out, n4);
        gemm_kernel<<<GEMM_BLOCKS, 256, 0, stream>>>(feat, W, support);
        spmm_kernel<<<(int)(((long)N_EDGES * 16 + 255) / 256), 256, 0, stream>>>(
            support, edge_val, edge_row, edge_col, out);
        relu_kernel<<<(n4 + 255) / 256, 256, 0, stream>>>((float4*)out, n4);
    }
}